// Round 21
// baseline (87.546 us; speedup 1.0000x reference)
//
#include <hip/hip_runtime.h>

// Fused masked 3x3 conv x2 (MinkowskiConv stride-1 equivalent), fp32 I/O:
//   m = float(mask); h = relu((conv3x3(x*m,w1)+b1)*m); out = (conv3x3(h,w2)+b2)*m
//
// R10 hybrid structure (LDS-staged inputs + in-register rolling compute;
// h NEVER touches LDS; ONE barrier; zero bank conflicts measured) fixed with
// everything proven since:
//  - s_xm staged as BF16 pairs (R20: absmax 0.125 << 0.4325 budget) ->
//    LDS 15.3 KB -> 8 blocks/CU (32 waves, 100% occupancy; R10 had 40%).
//  - XCD-chunked bijective swizzle (R16: each XCD owns one batch image,
//    tile-row fastest -> vertical halo = private-L2 hits; FETCH 196->144 MB).
//  - Non-temporal float4 stores (R11).
// Per wave: 8 iters x {1 ds_read_b64 + 1 u32 + 4 broadcast u32 + ~180 VALU}.
// Horizontal halos via 2 lane-shuffles per conv; band edges via uniform
// (broadcast) LDS reads. Vertical 3-taps roll through P/Q (conv1) and R/S
// (conv2) register pairs. Boundary rows/cols correct by construction:
// out-of-image staging writes 0 (x*m) and mask 0.

#define IMG_W 2048
#define IMG_H 2048
#define TB_W  256          // tile width  (one wave: 64 lanes x 4 cols)
#define TB_H  16           // tile height (4 waves x 4 rows)
#define SXW   264          // staged cols: image a-4 .. a+259
#define SXU   (SXW / 2)    // 132 u32 (bf16 pairs) per staged row
#define SY    20           // staged rows: r0-2 .. r0+17
#define MY    18           // mask rows:   r0-1 .. r0+16
#define NCH   (SXW / 4)    // 66 4-col chunks per staged row
#define NSTG  (SY * NCH)   // 1320

typedef float vf4 __attribute__((ext_vector_type(4)));

__device__ __forceinline__ unsigned pack_bf16_rtn(float a, float b) {
    unsigned ua = __float_as_uint(a), ub = __float_as_uint(b);
    ua = (ua + 0x8000u) >> 16;
    ub = (ub + 0x8000u) & 0xFFFF0000u;
    return ua | ub;
}
__device__ __forceinline__ float bf_lo(unsigned u) { return __uint_as_float(u << 16); }
__device__ __forceinline__ float bf_hi(unsigned u) { return __uint_as_float(u & 0xFFFF0000u); }

__global__ __launch_bounds__(256) void fused_mconv2(
    const float* __restrict__ x, const int* __restrict__ mask,
    const float* __restrict__ w1p, const float* __restrict__ b1p,
    const float* __restrict__ w2p, const float* __restrict__ b2p,
    float* __restrict__ out)
{
    __shared__ __align__(16) unsigned      s_xm[SY][SXU];  // bf16-pair x*m
    __shared__ __align__(4)  unsigned char s_m [MY][SXW];  // mask bytes

    // ---- XCD-chunked bijective swizzle (grid 8192 = 8 XCDs x 1024) ----
    // orig = xcd*1024 + slot; ty (tile row) fastest -> vertical-halo L2 hits;
    // tz = orig>>10 == xcd -> each XCD streams exactly one batch image.
    const int hw   = blockIdx.x;
    const int xcd  = hw & 7;
    const int slot = hw >> 3;                  // 0..1023
    const int orig = (xcd << 10) + slot;
    const int ty   = orig & 127;               // tile row (fastest)
    const int tx   = (orig >> 7) & 7;          // tile col
    const int tz   = orig >> 10;               // batch (== xcd)

    const int lane = threadIdx.x;              // 0..63
    const int wv   = threadIdx.y;              // 0..3
    const int tid  = wv * 64 + lane;
    const int a    = tx * TB_W;
    const int r0   = ty * TB_H;
    const size_t plane = (size_t)IMG_W * IMG_H;
    const float* xb = x    + (size_t)tz * plane;
    const int*   mb = mask + (size_t)tz * plane;
    float*       ob = out  + (size_t)tz * plane;

    float W1[9], W2[9];
    #pragma unroll
    for (int i = 0; i < 9; ++i) { W1[i] = w1p[i]; W2[i] = w2p[i]; }
    const float B1 = b1p[0], B2 = b2p[0];

    // ---- stage: x*m (bf16 pairs) + mask bytes, origin (r0-2, a-4) ----
    for (int idx = tid; idx < NSTG; idx += 256) {
        const int row = idx / NCH;
        const int k   = idx - row * NCH;
        const int r   = r0 - 2 + row;
        const int c   = a - 4 + (k << 2);
        float4 xm = make_float4(0.f, 0.f, 0.f, 0.f);
        unsigned mpack = 0u;
        if (r >= 0 && r < IMG_H && c >= 0 && c < IMG_W) {  // all-or-nothing 16B
            const size_t g = (size_t)r * IMG_W + c;
            const float4 xv = *reinterpret_cast<const float4*>(xb + g);
            const int4   mi = *reinterpret_cast<const int4*>(mb + g);
            xm.x = mi.x ? xv.x : 0.f;
            xm.y = mi.y ? xv.y : 0.f;
            xm.z = mi.z ? xv.z : 0.f;
            xm.w = mi.w ? xv.w : 0.f;
            mpack = (mi.x ? 1u : 0u) | (mi.y ? 256u : 0u) |
                    (mi.z ? 65536u : 0u) | (mi.w ? 16777216u : 0u);
        }
        uint2 p;
        p.x = pack_bf16_rtn(xm.x, xm.y);
        p.y = pack_bf16_rtn(xm.z, xm.w);
        *reinterpret_cast<uint2*>(&s_xm[row][k << 1]) = p;      // 8B aligned
        if (row >= 1 && row <= MY)                 // stage rows 1..18 -> mask 0..17
            *reinterpret_cast<unsigned*>(&s_m[row - 1][k << 2]) = mpack;
    }
    __syncthreads();

    // ---- per-wave register rolling over 4 output rows (8 iters) ----
    // Iter t consumes stage row srow=4wv+t (image row s=r0-2+4wv+t), computes
    // hm of image row s-1, and at t>=4 emits out row s-2 (r0+4wv+t-4).
    const int xup  = 2 + (lane << 1);          // lane's uint2 index (cols 4+4l..)
    const int mbp  = 4 + (lane << 2);          // lane's mask byte base
    const int ocol = a + (lane << 2);
    float P[4] = {0,0,0,0}, Q[4] = {0,0,0,0};
    float R[4] = {0,0,0,0}, S[4] = {0,0,0,0};
    float PE = 0, QE = 0, PR = 0, QR = 0;      // edge chains: h cols -1 / 256
    float mq[4] = {0,0,0,0};                   // out-row mask (prev iter's mf)

    #pragma unroll
    for (int t = 0; t < 8; ++t) {
        const int srow = (wv << 2) + t;                         // 0..19
        const uint2 xp = *reinterpret_cast<const uint2*>(&s_xm[srow][xup]);
        const unsigned eLu = s_xm[srow][1];     // stage cols 2,3
        const unsigned eRu = s_xm[srow][130];   // stage cols 260,261
        int mi_ = (wv << 2) + t - 2;            // mask row of h row s-1
        mi_ = mi_ < 0 ? 0 : mi_;                // clamp (priming iters only)
        const unsigned mw  = *reinterpret_cast<const unsigned*>(&s_m[mi_][mbp]);
        const unsigned mwL = *reinterpret_cast<const unsigned*>(&s_m[mi_][0]);
        const unsigned mwR = *reinterpret_cast<const unsigned*>(&s_m[mi_][260]);
        float mf[4];
        mf[0] = (float)(mw & 255u);         mf[1] = (float)((mw >> 8) & 255u);
        mf[2] = (float)((mw >> 16) & 255u); mf[3] = (float)((mw >> 24) & 255u);
        const float mEL = (float)((mwL >> 24) & 255u);   // mask @ col 3 (h col -1)
        const float mER = (float)(mwR & 255u);           // mask @ col 260 (h col 256)

        const float eLx0 = bf_lo(eLu), eLx1 = bf_hi(eLu);   // cols 2,3
        const float eRx0 = bf_lo(eRu), eRx1 = bf_hi(eRu);   // cols 260,261
        float t_[6];                            // xm window: cols col-1..col+4
        t_[1] = bf_lo(xp.x); t_[2] = bf_hi(xp.x);
        t_[3] = bf_lo(xp.y); t_[4] = bf_hi(xp.y);
        const float upx = __shfl_up(t_[4], 1);
        const float dnx = __shfl_down(t_[1], 1);
        t_[0] = (lane == 0)  ? eLx1 : upx;
        t_[5] = (lane == 63) ? eRx0 : dnx;

        // conv1 dots + vertical roll: hm = masked relu of h row s-1
        float hm[4];
        #pragma unroll
        for (int c = 0; c < 4; ++c) {
            const float u0 = W1[0]*t_[c] + W1[1]*t_[c+1] + W1[2]*t_[c+2];
            const float u1 = W1[3]*t_[c] + W1[4]*t_[c+1] + W1[5]*t_[c+2];
            const float u2 = W1[6]*t_[c] + W1[7]*t_[c+1] + W1[8]*t_[c+2];
            const float h  = Q[c] + u2 + B1;
            hm[c] = fmaxf(h, 0.f) * mf[c];
            Q[c] = P[c] + u1;
            P[c] = u0;
        }
        // edge h col -1 (lane 0): taps cols 2,3,4 = eLx0, eLx1, t_[1]
        float hmE, hmRv;
        {
            const float u0 = W1[0]*eLx0 + W1[1]*eLx1 + W1[2]*t_[1];
            const float u1 = W1[3]*eLx0 + W1[4]*eLx1 + W1[5]*t_[1];
            const float u2 = W1[6]*eLx0 + W1[7]*eLx1 + W1[8]*t_[1];
            const float h  = QE + u2 + B1;
            hmE = fmaxf(h, 0.f) * mEL;
            QE = PE + u1;  PE = u0;
        }
        // edge h col 256 (lane 63): taps cols 259,260,261 = t_[4], eRx0, eRx1
        {
            const float u0 = W1[0]*t_[4] + W1[1]*eRx0 + W1[2]*eRx1;
            const float u1 = W1[3]*t_[4] + W1[4]*eRx0 + W1[5]*eRx1;
            const float u2 = W1[6]*t_[4] + W1[7]*eRx0 + W1[8]*eRx1;
            const float h  = QR + u2 + B1;
            hmRv = fmaxf(h, 0.f) * mER;
            QR = PR + u1;  PR = u0;
        }

        // conv2 on hm row s-1
        float g_[6];
        g_[1] = hm[0]; g_[2] = hm[1]; g_[3] = hm[2]; g_[4] = hm[3];
        const float uph = __shfl_up(hm[3], 1);
        const float dnh = __shfl_down(hm[0], 1);
        g_[0] = (lane == 0)  ? hmE  : uph;
        g_[5] = (lane == 63) ? hmRv : dnh;

        float v0[4], v1[4], v2[4];
        #pragma unroll
        for (int c = 0; c < 4; ++c) {
            v0[c] = W2[0]*g_[c] + W2[1]*g_[c+1] + W2[2]*g_[c+2];
            v1[c] = W2[3]*g_[c] + W2[4]*g_[c+1] + W2[5]*g_[c+2];
            v2[c] = W2[6]*g_[c] + W2[7]*g_[c+1] + W2[8]*g_[c+2];
        }
        if (t >= 4) {                           // emit out row r0+4wv+t-4
            const int orow = r0 + (wv << 2) + t - 4;
            vf4 o;
            o.x = (S[0] + v2[0] + B2) * mq[0];
            o.y = (S[1] + v2[1] + B2) * mq[1];
            o.z = (S[2] + v2[2] + B2) * mq[2];
            o.w = (S[3] + v2[3] + B2) * mq[3];
            __builtin_nontemporal_store(
                o, reinterpret_cast<vf4*>(ob + (size_t)orow * IMG_W + ocol));
        }
        #pragma unroll
        for (int c = 0; c < 4; ++c) { S[c] = R[c] + v1[c]; R[c] = v0[c]; }
        #pragma unroll
        for (int c = 0; c < 4; ++c) { mq[c] = mf[c]; }
    }
}

extern "C" void kernel_launch(void* const* d_in, const int* in_sizes, int n_in,
                              void* d_out, int out_size, void* d_ws, size_t ws_size,
                              hipStream_t stream) {
    const float* x    = (const float*)d_in[0];
    const int*   mask = (const int*)  d_in[1];
    const float* w1   = (const float*)d_in[2];
    const float* b1   = (const float*)d_in[3];
    const float* w2   = (const float*)d_in[4];
    const float* b2   = (const float*)d_in[5];
    float*       out  = (float*)d_out;

    dim3 block(64, 4, 1);
    dim3 grid(8192, 1, 1);    // 8 tile-cols x 128 tile-rows x 8 images, swizzled
    hipLaunchKernelGGL(fused_mconv2, grid, block, 0, stream,
                       x, mask, w1, b1, w2, b2, out);
}

// Round 22
// 75.239 us; speedup vs baseline: 1.1636x; 1.1636x over previous
//
#include <hip/hip_runtime.h>

// Fused masked 3x3 conv x2 (MinkowskiConv stride-1 equivalent), fp32 I/O:
//   m = float(mask); h = relu((conv3x3(x*m,w1)+b1)*m); out = (conv3x3(h,w2)+b2)*m
// R20 (best: bf16-staged s_xm, conv1 quads with b64 taps, conv2 quads with
// b128 taps, enc-sign folding, XCD swizzle, NT vf4 stores) + 2-TILE
// SINGLE-BUFFER PIPELINE: each block does two vertically-adjacent tiles;
// tile-B's global loads are issued into registers right after bar1, so
// their HBM/L2 latency rides under conv1(A)+conv2(A). LDS stays 17.7 KB
// (no R18 occupancy collapse); block count halves.

#define TB_W 128
#define TB_H 16
#define SX   136           // staged width: TB_W + 8
#define SY   20            // staged height: TB_H + 4
#define NV4  (SX / 4)      // 34 chunks per staged row
#define NSTG (SY * NV4)    // 680
#define HR   18            // h rows
#define NQR  33            // conv1 quads per h row
#define NQ   (HR * NQR)    // 594
#define IMG_W 2048
#define IMG_H 2048

typedef float vf4 __attribute__((ext_vector_type(4)));

__device__ __forceinline__ unsigned pack_bf16_rtn(float a, float b) {
    unsigned ua = __float_as_uint(a), ub = __float_as_uint(b);
    ua = (ua + 0x8000u) >> 16;
    ub = (ub + 0x8000u) & 0xFFFF0000u;
    return ua | ub;
}
__device__ __forceinline__ float bf_lo(unsigned u) { return __uint_as_float(u << 16); }
__device__ __forceinline__ float bf_hi(unsigned u) { return __uint_as_float(u & 0xFFFF0000u); }

__global__ __launch_bounds__(256) void fused_mconv2(
    const float* __restrict__ x, const int* __restrict__ mask,
    const float* __restrict__ w1p, const float* __restrict__ b1p,
    const float* __restrict__ w2p, const float* __restrict__ b2p,
    float* __restrict__ out)
{
    __shared__ __align__(16) unsigned s_xm[SY][SX / 2];   // bf16 pairs
    __shared__ __align__(16) float    s_hm[HR][SX];       // enc(h,m)
    __shared__ __align__(4)  unsigned char s_mb[HR][SX];  // mask bytes

    // ---- XCD-chunked bijective swizzle (grid 8192 = 8 XCDs x 1024) ----
    // XCD k owns batch image k; 32-row band varies fastest.
    const int hw   = blockIdx.x;
    const int xcd  = hw & 7;
    const int slot = hw >> 3;                 // 0..1023
    const int orig = (xcd << 10) + slot;
    const int band = orig & 63;               // 0..63 (fastest)
    const int cl   = orig >> 6;
    const int tx   = cl & 15;                 // tile col 0..15
    const int tz   = cl >> 4;                 // batch 0..7 (== xcd)

    const int tid  = threadIdx.y * 64 + threadIdx.x;
    const int c0   = tx * TB_W;
    const int r0A  = band * (2 * TB_H);
    const int r0B  = r0A + TB_H;
    const size_t plane = (size_t)IMG_W * IMG_H;
    const float* xb = x    + (size_t)tz * plane;
    const int*   mb = mask + (size_t)tz * plane;
    float*       ob = out  + (size_t)tz * plane;

    float W1[9], W2[9];
    #pragma unroll
    for (int i = 0; i < 9; ++i) { W1[i] = w1p[i]; W2[i] = w2p[i]; }
    const float B1 = b1p[0], B2 = b2p[0];

    float4 xr[3]; int4 mr[3];    // prefetch regs, time-shared between tiles

    // ---- branch-free clamped issue of one tile's stage loads ----
    auto issue_loads = [&](int r0t) {
        #pragma unroll
        for (int u = 0; u < 3; ++u) {
            int idx = tid + (u << 8);
            idx = idx < NSTG ? idx : NSTG - 1;
            const int row  = idx / NV4;
            const int col4 = idx - row * NV4;
            int r = r0t - 2 + row;
            int c = c0 - 4 + (col4 << 2);
            r = r < 0 ? 0 : (r > IMG_H - 1 ? IMG_H - 1 : r);
            c = c < 0 ? 0 : (c > IMG_W - 4 ? IMG_W - 4 : c);
            const size_t g = (size_t)r * IMG_W + c;
            xr[u] = *reinterpret_cast<const float4*>(xb + g);
            mr[u] = *reinterpret_cast<const int4*>(mb + g);
        }
    };
    // ---- write staged regs into LDS (validity applied here) ----
    auto stage_write = [&](int r0t) {
        #pragma unroll
        for (int u = 0; u < 3; ++u) {
            const int idx = tid + (u << 8);
            if (idx < NSTG) {
                const int row  = idx / NV4;
                const int col4 = idx - row * NV4;
                const int r = r0t - 2 + row;
                const int c = c0 - 4 + (col4 << 2);
                float4 xm = make_float4(0.f, 0.f, 0.f, 0.f);
                unsigned mpack = 0u;
                if (r >= 0 && r < IMG_H && c >= 0 && c < IMG_W) {
                    const float4 xv = xr[u];
                    const int4   mi = mr[u];
                    xm.x = mi.x ? xv.x : 0.f;
                    xm.y = mi.y ? xv.y : 0.f;
                    xm.z = mi.z ? xv.z : 0.f;
                    xm.w = mi.w ? xv.w : 0.f;
                    mpack = (mi.x ? 1u : 0u) | (mi.y ? 256u : 0u) |
                            (mi.z ? 65536u : 0u) | (mi.w ? 16777216u : 0u);
                }
                uint2 p;
                p.x = pack_bf16_rtn(xm.x, xm.y);
                p.y = pack_bf16_rtn(xm.z, xm.w);
                *reinterpret_cast<uint2*>(&s_xm[row][col4 << 1]) = p;
                if (row >= 1 && row <= HR)
                    *reinterpret_cast<unsigned*>(&s_mb[row - 1][col4 << 2]) = mpack;
            }
        }
    };

    // ---- conv1 QUADS (bf16 taps), R20 verbatim ----
    auto conv1 = [&]() {
        for (int idx = tid; idx < NQ; idx += 256) {
            const int hr = idx / NQR;
            const int q  = idx - hr * NQR;
            const int hc = q << 2;
            float a0 = B1, a1 = B1, a2 = B1, a3 = B1;
            #pragma unroll
            for (int di = 0; di < 3; ++di) {
                const unsigned* xrp = &s_xm[hr + di][q << 1];
                const uint2 A  = *reinterpret_cast<const uint2*>(xrp);
                const uint2 Bv = *reinterpret_cast<const uint2*>(xrp + 2);
                const float c2 = bf_lo(A.y),  c3 = bf_hi(A.y);
                const float c4 = bf_lo(Bv.x), c5 = bf_hi(Bv.x);
                const float c6 = bf_lo(Bv.y), c7 = bf_hi(Bv.y);
                const float w0 = W1[di * 3], w1 = W1[di * 3 + 1], w2 = W1[di * 3 + 2];
                a0 += w0 * c2 + w1 * c3 + w2 * c4;
                a1 += w0 * c3 + w1 * c4 + w2 * c5;
                a2 += w0 * c4 + w1 * c5 + w2 * c6;
                a3 += w0 * c5 + w1 * c6 + w2 * c7;
            }
            const unsigned mA = *reinterpret_cast<const unsigned*>(&s_mb[hr][hc]);
            const unsigned mB = *reinterpret_cast<const unsigned*>(&s_mb[hr][hc + 4]);
            float4 e;
            e.x = ((mA >> 24) & 255u) ? fmaxf(a0, 0.f) : -1.0f;
            e.y = ( mB        & 255u) ? fmaxf(a1, 0.f) : -1.0f;
            e.z = ((mB >>  8) & 255u) ? fmaxf(a2, 0.f) : -1.0f;
            e.w = ((mB >> 16) & 255u) ? fmaxf(a3, 0.f) : -1.0f;
            *reinterpret_cast<float4*>(&s_hm[hr][hc]) = e;
        }
    };

    // ---- conv2 QUADS (b128 taps, vertical rolling, NT stores), R20 ----
    auto conv2 = [&](int r0t) {
        const int q     = tid & 31;
        const int strip = tid >> 5;          // 0..7
        const int i0    = strip << 1;
        const int jc    = q << 2;
        float P[4] = {0,0,0,0}, Q[4] = {0,0,0,0}, cm[4] = {0,0,0,0};
        #pragma unroll
        for (int t = 0; t < 4; ++t) {
            const int hr = i0 + t;
            const float4 E1 = *reinterpret_cast<const float4*>(&s_hm[hr][jc]);
            const float4 E2 = *reinterpret_cast<const float4*>(&s_hm[hr][jc + 4]);
            const float v0 = E1.x, v1 = E1.y, v2 = E1.z, v3 = E1.w;
            const float v4 = E2.x, v5 = E2.y;
            const float r0 = fmaxf(v0, 0.f), r1 = fmaxf(v1, 0.f);
            const float r2 = fmaxf(v2, 0.f), r3 = fmaxf(v3, 0.f);
            const float r4 = fmaxf(v4, 0.f), r5 = fmaxf(v5, 0.f);
            float d0[4], d1[4], d2[4];
            d0[0] = W2[0]*r0 + W2[1]*r1 + W2[2]*r2;
            d0[1] = W2[0]*r1 + W2[1]*r2 + W2[2]*r3;
            d0[2] = W2[0]*r2 + W2[1]*r3 + W2[2]*r4;
            d0[3] = W2[0]*r3 + W2[1]*r4 + W2[2]*r5;
            d1[0] = W2[3]*r0 + W2[4]*r1 + W2[5]*r2;
            d1[1] = W2[3]*r1 + W2[4]*r2 + W2[5]*r3;
            d1[2] = W2[3]*r2 + W2[4]*r3 + W2[5]*r4;
            d1[3] = W2[3]*r3 + W2[4]*r4 + W2[5]*r5;
            d2[0] = W2[6]*r0 + W2[7]*r1 + W2[8]*r2;
            d2[1] = W2[6]*r1 + W2[7]*r2 + W2[8]*r3;
            d2[2] = W2[6]*r2 + W2[7]*r3 + W2[8]*r4;
            d2[3] = W2[6]*r3 + W2[7]*r4 + W2[8]*r5;
            if (t >= 2) {
                const int i = i0 + t - 2;
                vf4 o;
                o.x = (cm[0] >= 0.f) ? (Q[0] + d2[0] + B2) : 0.f;
                o.y = (cm[1] >= 0.f) ? (Q[1] + d2[1] + B2) : 0.f;
                o.z = (cm[2] >= 0.f) ? (Q[2] + d2[2] + B2) : 0.f;
                o.w = (cm[3] >= 0.f) ? (Q[3] + d2[3] + B2) : 0.f;
                __builtin_nontemporal_store(
                    o, reinterpret_cast<vf4*>(
                           ob + (size_t)(r0t + i) * IMG_W + (c0 + jc)));
            }
            #pragma unroll
            for (int c = 0; c < 4; ++c) { Q[c] = P[c] + d1[c]; P[c] = d0[c]; }
            cm[0] = v1; cm[1] = v2; cm[2] = v3; cm[3] = v4;
        }
    };

    // ================= 2-tile single-buffer pipeline =================
    issue_loads(r0A);
    stage_write(r0A);
    __syncthreads();                  // bar1: tile-A staged

    issue_loads(r0B);                 // B loads fly under conv1(A)+conv2(A)
    conv1();
    __syncthreads();                  // bar2: conv1(A) done reading s_xm/s_mb

    stage_write(r0B);                 // overwrite s_xm/s_mb (safe post-bar2)
    conv2(r0A);                       // reads s_hm only
    __syncthreads();                  // bar3: B staged AND s_hm free

    conv1();
    __syncthreads();                  // bar4

    conv2(r0B);
}

extern "C" void kernel_launch(void* const* d_in, const int* in_sizes, int n_in,
                              void* d_out, int out_size, void* d_ws, size_t ws_size,
                              hipStream_t stream) {
    const float* x    = (const float*)d_in[0];
    const int*   mask = (const int*)  d_in[1];
    const float* w1   = (const float*)d_in[2];
    const float* b1   = (const float*)d_in[3];
    const float* w2   = (const float*)d_in[4];
    const float* b2   = (const float*)d_in[5];
    float*       out  = (float*)d_out;

    dim3 block(64, 4, 1);
    dim3 grid(8192, 1, 1);            // 8 XCDs x 1024 (bijective swizzle)
    hipLaunchKernelGGL(fused_mconv2, grid, block, 0, stream,
                       x, mask, w1, b1, w2, b2, out);
}

// Round 23
// 71.782 us; speedup vs baseline: 1.2196x; 1.0482x over previous
//
#include <hip/hip_runtime.h>

// Fused masked 3x3 conv x2 (MinkowskiConv stride-1 equivalent), fp32 I/O:
//   m = float(mask); h = relu((conv3x3(x*m,w1)+b1)*m); out = (conv3x3(h,w2)+b2)*m
// FINAL (= round-20 best, 72.0 us): LDS-tiled 128x16, all LDS access via
// aligned conflict-free quads, enc-sign mask folding, XCD-chunked swizzle,
// bf16 staging (absmax 0.125 << 0.4325 budget), non-temporal vf4 stores.
//  - stage: x*m as bf16 pairs + mask bytes (float4/int4 global loads)
//  - conv1 QUADS: 2x ds_read_b64 serve 4 h-points; fp32 accumulate;
//    enc = m ? relu(h) : -1 written as one aligned b128
//  - conv2 QUADS: 2x ds_read_b128 per row, vertical register rolling,
//    center-enc sign carries the output mask; float4 NT stores
// Logical traffic 384 MB -> 5.3 TB/s effective = 85% of copy ceiling.

#define TB_W 128
#define TB_H 16
#define SX   136           // staged width: TB_W + 8
#define SY   20            // staged height: TB_H + 4
#define NV4  (SX / 4)      // 34 chunks per staged row
#define NSTG (SY * NV4)    // 680
#define HR   18            // h rows
#define NQR  33            // conv1 quads per h row
#define NQ   (HR * NQR)    // 594
#define IMG_W 2048
#define IMG_H 2048

typedef float vf4 __attribute__((ext_vector_type(4)));

__device__ __forceinline__ unsigned pack_bf16_rtn(float a, float b) {
    unsigned ua = __float_as_uint(a), ub = __float_as_uint(b);
    ua = (ua + 0x8000u) >> 16;
    ub = (ub + 0x8000u) & 0xFFFF0000u;
    return ua | ub;
}
__device__ __forceinline__ float bf_lo(unsigned u) { return __uint_as_float(u << 16); }
__device__ __forceinline__ float bf_hi(unsigned u) { return __uint_as_float(u & 0xFFFF0000u); }

__global__ __launch_bounds__(256) void fused_mconv2(
    const float* __restrict__ x, const int* __restrict__ mask,
    const float* __restrict__ w1p, const float* __restrict__ b1p,
    const float* __restrict__ w2p, const float* __restrict__ b2p,
    float* __restrict__ out)
{
    __shared__ __align__(16) unsigned s_xm[SY][SX / 2];   // bf16 pairs (68 u32/row)
    __shared__ __align__(16) float    s_hm[HR][SX];       // enc(h,m) at word hcol
    __shared__ __align__(4)  unsigned char s_mb[HR][SX];  // mask bytes

    // ---- XCD-chunked bijective block swizzle (grid 16384 = 8 x 2048) ----
    const int hw   = (blockIdx.z * gridDim.y + blockIdx.y) * gridDim.x + blockIdx.x;
    const int xcd  = hw & 7;
    const int slot = hw >> 3;
    const int orig = (xcd << 11) + slot;      // XCD k owns [2048k, 2048k+2048)
    const int ty   = orig & 127;              // tile row (fastest)
    const int cl   = orig >> 7;
    const int tx   = cl & 15;                 // tile col
    const int tz   = cl >> 4;                 // batch (== xcd)

    const int tid  = threadIdx.y * 64 + threadIdx.x;
    const int c0   = tx * TB_W;
    const int row0 = ty * TB_H;
    const size_t plane = (size_t)IMG_W * IMG_H;
    const float* xb = x    + (size_t)tz * plane;
    const int*   mb = mask + (size_t)tz * plane;
    float*       ob = out  + (size_t)tz * plane;

    float W1[9], W2[9];
    #pragma unroll
    for (int i = 0; i < 9; ++i) { W1[i] = w1p[i]; W2[i] = w2p[i]; }
    const float B1 = b1p[0], B2 = b2p[0];

    // ---- stage: x*m as bf16 pairs + mask bytes, origin (row0-2, c0-4) ----
    for (int idx = tid; idx < NSTG; idx += 256) {
        const int row  = idx / NV4;
        const int col4 = idx - row * NV4;
        const int r = row0 - 2 + row;
        const int c = c0 - 4 + (col4 << 2);
        float4 xm = make_float4(0.f, 0.f, 0.f, 0.f);
        unsigned mpack = 0u;
        if (r >= 0 && r < IMG_H && c >= 0 && c < IMG_W) {   // all-or-nothing 16B
            const size_t g = (size_t)r * IMG_W + c;
            const float4 xv = *reinterpret_cast<const float4*>(xb + g);
            const int4   mi = *reinterpret_cast<const int4*>(mb + g);
            xm.x = mi.x ? xv.x : 0.f;
            xm.y = mi.y ? xv.y : 0.f;
            xm.z = mi.z ? xv.z : 0.f;
            xm.w = mi.w ? xv.w : 0.f;
            mpack = (mi.x ? 1u : 0u) | (mi.y ? 256u : 0u) |
                    (mi.z ? 65536u : 0u) | (mi.w ? 16777216u : 0u);
        }
        uint2 p;
        p.x = pack_bf16_rtn(xm.x, xm.y);
        p.y = pack_bf16_rtn(xm.z, xm.w);
        *reinterpret_cast<uint2*>(&s_xm[row][col4 << 1]) = p;   // 8B aligned
        if (row >= 1 && row <= HR)
            *reinterpret_cast<unsigned*>(&s_mb[row - 1][col4 << 2]) = mpack;
    }
    __syncthreads();

    // ---- conv1 QUADS (bf16 taps): 4 points/thread ----
    // Quad hc=4q: points hc..hc+3 tap stage cols hc+2..hc+7; read pairs
    // [2q..2q+1] and [2q+2..2q+3] as two uint2 (8B aligned).
    for (int idx = tid; idx < NQ; idx += 256) {
        const int hr = idx / NQR;
        const int q  = idx - hr * NQR;
        const int hc = q << 2;
        float a0 = B1, a1 = B1, a2 = B1, a3 = B1;
        #pragma unroll
        for (int di = 0; di < 3; ++di) {
            const unsigned* xr = &s_xm[hr + di][q << 1];
            const uint2 A  = *reinterpret_cast<const uint2*>(xr);
            const uint2 Bv = *reinterpret_cast<const uint2*>(xr + 2);
            const float c2 = bf_lo(A.y),  c3 = bf_hi(A.y);
            const float c4 = bf_lo(Bv.x), c5 = bf_hi(Bv.x);
            const float c6 = bf_lo(Bv.y), c7 = bf_hi(Bv.y);
            const float w0 = W1[di * 3], w1 = W1[di * 3 + 1], w2 = W1[di * 3 + 2];
            a0 += w0 * c2 + w1 * c3 + w2 * c4;
            a1 += w0 * c3 + w1 * c4 + w2 * c5;
            a2 += w0 * c4 + w1 * c5 + w2 * c6;
            a3 += w0 * c5 + w1 * c6 + w2 * c7;
        }
        const unsigned mA = *reinterpret_cast<const unsigned*>(&s_mb[hr][hc]);
        const unsigned mB = *reinterpret_cast<const unsigned*>(&s_mb[hr][hc + 4]);
        float4 e;
        e.x = ((mA >> 24) & 255u) ? fmaxf(a0, 0.f) : -1.0f;
        e.y = ( mB        & 255u) ? fmaxf(a1, 0.f) : -1.0f;
        e.z = ((mB >>  8) & 255u) ? fmaxf(a2, 0.f) : -1.0f;
        e.w = ((mB >> 16) & 255u) ? fmaxf(a3, 0.f) : -1.0f;
        *reinterpret_cast<float4*>(&s_hm[hr][hc]) = e;   // 16B aligned
    }
    __syncthreads();

    // ---- conv2 QUADS: 4 out cols/thread, 2 aligned b128/row, rolling ----
    // out(i, 4q+c) taps s_hm rows i..i+2, words 4q+c..4q+c+2 (c=0..3) ->
    // words 4q..4q+5 from float4 at [4q] and [4q+4]. 8 strips x 2 rows.
    {
        const int q     = tid & 31;          // quad -> out cols 4q..4q+3
        const int strip = tid >> 5;          // 0..7
        const int i0    = strip << 1;        // out rows i0, i0+1
        const int jc    = q << 2;
        float P[4] = {0,0,0,0}, Q[4] = {0,0,0,0}, cm[4] = {0,0,0,0};
        #pragma unroll
        for (int t = 0; t < 4; ++t) {
            const int hr = i0 + t;
            const float4 E1 = *reinterpret_cast<const float4*>(&s_hm[hr][jc]);
            const float4 E2 = *reinterpret_cast<const float4*>(&s_hm[hr][jc + 4]);
            const float v0 = E1.x, v1 = E1.y, v2 = E1.z, v3 = E1.w;
            const float v4 = E2.x, v5 = E2.y;
            const float r0 = fmaxf(v0, 0.f), r1 = fmaxf(v1, 0.f);
            const float r2 = fmaxf(v2, 0.f), r3 = fmaxf(v3, 0.f);
            const float r4 = fmaxf(v4, 0.f), r5 = fmaxf(v5, 0.f);
            float d0[4], d1[4], d2[4];
            d0[0] = W2[0]*r0 + W2[1]*r1 + W2[2]*r2;
            d0[1] = W2[0]*r1 + W2[1]*r2 + W2[2]*r3;
            d0[2] = W2[0]*r2 + W2[1]*r3 + W2[2]*r4;
            d0[3] = W2[0]*r3 + W2[1]*r4 + W2[2]*r5;
            d1[0] = W2[3]*r0 + W2[4]*r1 + W2[5]*r2;
            d1[1] = W2[3]*r1 + W2[4]*r2 + W2[5]*r3;
            d1[2] = W2[3]*r2 + W2[4]*r3 + W2[5]*r4;
            d1[3] = W2[3]*r3 + W2[4]*r4 + W2[5]*r5;
            d2[0] = W2[6]*r0 + W2[7]*r1 + W2[8]*r2;
            d2[1] = W2[6]*r1 + W2[7]*r2 + W2[8]*r3;
            d2[2] = W2[6]*r2 + W2[7]*r3 + W2[8]*r4;
            d2[3] = W2[6]*r3 + W2[7]*r4 + W2[8]*r5;
            if (t >= 2) {
                const int i = i0 + t - 2;
                vf4 o;
                o.x = (cm[0] >= 0.f) ? (Q[0] + d2[0] + B2) : 0.f;
                o.y = (cm[1] >= 0.f) ? (Q[1] + d2[1] + B2) : 0.f;
                o.z = (cm[2] >= 0.f) ? (Q[2] + d2[2] + B2) : 0.f;
                o.w = (cm[3] >= 0.f) ? (Q[3] + d2[3] + B2) : 0.f;
                __builtin_nontemporal_store(
                    o, reinterpret_cast<vf4*>(
                           ob + (size_t)(row0 + i) * IMG_W + (c0 + jc)));
            }
            #pragma unroll
            for (int c = 0; c < 4; ++c) { Q[c] = P[c] + d1[c]; P[c] = d0[c]; }
            cm[0] = v1; cm[1] = v2; cm[2] = v3; cm[3] = v4;   // enc centers
        }
    }
}

extern "C" void kernel_launch(void* const* d_in, const int* in_sizes, int n_in,
                              void* d_out, int out_size, void* d_ws, size_t ws_size,
                              hipStream_t stream) {
    const float* x    = (const float*)d_in[0];
    const int*   mask = (const int*)  d_in[1];
    const float* w1   = (const float*)d_in[2];
    const float* b1   = (const float*)d_in[3];
    const float* w2   = (const float*)d_in[4];
    const float* b2   = (const float*)d_in[5];
    float*       out  = (float*)d_out;

    dim3 block(64, 4, 1);
    dim3 grid(IMG_W / TB_W, IMG_H / TB_H, 8);   // 16 x 128 x 8 = 16384
    hipLaunchKernelGGL(fused_mconv2, grid, block, 0, stream,
                       x, mask, w1, b1, w2, b2, out);
}